// Round 8
// baseline (615.487 us; speedup 1.0000x reference)
//
#include <hip/hip_runtime.h>
#include <hip/hip_bf16.h>
#include <stdint.h>

typedef float floatx2 __attribute__((ext_vector_type(2)));

#define NPB 256          // nodes per bucket (node>>8)
#define NB 391           // ceil(100000/256)
#define NBLKA 512        // blocks in pass A (A1/A2 must match)

__device__ __forceinline__ float rdlane(float v, int l) {
    return __uint_as_float(__builtin_amdgcn_readlane(__float_as_uint(v), l));
}
// pack 4 floats -> 4 fp8 e4m3 (HW cvt, RNE)
__device__ __forceinline__ unsigned pk_fp8x4(float a, float b, float c, float d) {
    int u = __builtin_amdgcn_cvt_pk_fp8_f32(a, b, 0, false);
    u = __builtin_amdgcn_cvt_pk_fp8_f32(c, d, u, true);
    return (unsigned)u;
}
__device__ __forceinline__ unsigned pk_fp8x2(float a, float b) {
    return (unsigned)__builtin_amdgcn_cvt_pk_fp8_f32(a, b, 0, false);
}

// ---------------- zero inTot + pooled sums ----------------------------------
__global__ __launch_bounds__(512) void k_zero(int* __restrict__ inTot,
                                              double* __restrict__ sums) {
    int t = threadIdx.x;
    if (t < 128) sums[t] = 0.0;
    if (t < NB) inTot[t] = 0;
}

// ------- A1: per-block record->bucket histogram (no global scatter) ---------
__global__ __launch_bounds__(256) void k_A1(const int* __restrict__ ei,
                                            int* __restrict__ h,
                                            int* __restrict__ inTot,
                                            int E, int epb) {
    __shared__ int hist[NB], histIn[NB];
    int t = threadIdx.x, blk = blockIdx.x;
    for (int b = t; b < NB; b += 256) { hist[b] = 0; histIn[b] = 0; }
    __syncthreads();
    int e0 = blk * epb, e1 = min(E, e0 + epb);
    for (int e = e0 + t; e < e1; e += 256) {
        int s = ei[e], d = ei[E + e];
        atomicAdd(&hist[s >> 8], 1);   // out-record
        atomicAdd(&hist[d >> 8], 1);   // in-record
        atomicAdd(&histIn[d >> 8], 1);
    }
    __syncthreads();
    for (int b = t; b < NB; b += 256) {
        h[(size_t)b * NBLKA + blk] = hist[b];
        if (histIn[b]) atomicAdd(&inTot[b], histIn[b]);
    }
}

// ---------------- int scans (512-thread, 3-pass, in-place) ------------------
__global__ __launch_bounds__(512) void k_sc1(const int* __restrict__ v,
                                             int* __restrict__ bsum, int n) {
    __shared__ int l[512];
    int i = blockIdx.x * 512 + threadIdx.x;
    l[threadIdx.x] = (i < n) ? v[i] : 0;
    __syncthreads();
    for (int s = 256; s > 0; s >>= 1) {
        if (threadIdx.x < s) l[threadIdx.x] += l[threadIdx.x + s];
        __syncthreads();
    }
    if (threadIdx.x == 0) bsum[blockIdx.x] = l[0];
}
__global__ __launch_bounds__(512) void k_sc2(int* __restrict__ bsum, int nb) {
    __shared__ int l[512];
    int t = threadIdx.x;
    int v = (t < nb) ? bsum[t] : 0;
    l[t] = v;
    __syncthreads();
    for (int s = 1; s < 512; s <<= 1) {
        int tmp = (t >= s) ? l[t - s] : 0;
        __syncthreads();
        l[t] += tmp;
        __syncthreads();
    }
    if (t < nb) bsum[t] = l[t] - v;  // exclusive
}
__global__ __launch_bounds__(512) void k_sc3(int* __restrict__ v,
                                             const int* __restrict__ bsum, int n) {
    __shared__ int l[512];
    int i = blockIdx.x * 512 + threadIdx.x;
    int x = (i < n) ? v[i] : 0;
    l[threadIdx.x] = x;
    __syncthreads();
    for (int s = 1; s < 512; s <<= 1) {
        int tmp = (threadIdx.x >= (unsigned)s) ? l[threadIdx.x - s] : 0;
        __syncthreads();
        l[threadIdx.x] += tmp;
        __syncthreads();
    }
    if (i < n) v[i] = l[threadIdx.x] - x + bsum[blockIdx.x];
}
// exclusive scan of inTot[NB] -> inBase[NB] (single block)
__global__ __launch_bounds__(512) void k_scanIn(const int* __restrict__ inTot,
                                                int* __restrict__ inBase) {
    __shared__ int l[512];
    int t = threadIdx.x;
    int v = (t < NB) ? inTot[t] : 0;
    l[t] = v;
    __syncthreads();
    for (int s = 1; s < 512; s <<= 1) {
        int tmp = (t >= s) ? l[t - s] : 0;
        __syncthreads();
        l[t] += tmp;
        __syncthreads();
    }
    if (t < NB) inBase[t] = l[t] - v;
}

// ------- A2: edge MLP + bucketed record scatter (LDS cursors, no atomics) ---
// record uint4: x=(node<<1)|isIn  y=src(in only)  z=ef fp8[0..3]  w=ef fp8[4..5]
__global__ __launch_bounds__(256) void k_A2(
    const int* __restrict__ ei, const float* __restrict__ ea,
    const float* __restrict__ We1, const float* __restrict__ be1,
    const float* __restrict__ We2, const float* __restrict__ be2,
    const int* __restrict__ hs, uint4* __restrict__ rec, int E, int epb) {
    __shared__ float sWe1[128], sbe1[64], sWe2[64 * 6], sbe2[6];
    __shared__ int cur[NB];
    int t = threadIdx.x, blk = blockIdx.x;
    if (t < 128) sWe1[t] = We1[t];
    if (t < 64) {
        sbe1[t] = be1[t];
#pragma unroll
        for (int c = 0; c < 6; ++c) sWe2[t * 6 + c] = We2[t * 64 + c];
    }
    if (t < 6) sbe2[t] = be2[t];
    for (int b = t; b < NB; b += 256) cur[b] = hs[(size_t)b * NBLKA + blk];
    __syncthreads();

    int e0 = blk * epb, e1 = min(E, e0 + epb);
    for (int e = e0 + t; e < e1; e += 256) {
        int s = ei[e], d = ei[E + e];
        float2 aa = ((const float2*)ea)[e];
        float acc[6];
#pragma unroll
        for (int c = 0; c < 6; ++c) acc[c] = sbe2[c];
#pragma unroll
        for (int j = 0; j < 64; ++j) {
            float hh = fmaf(aa.x, sWe1[j], fmaf(aa.y, sWe1[64 + j], sbe1[j]));
            hh = fmaxf(hh, 0.f);
#pragma unroll
            for (int c = 0; c < 6; ++c) acc[c] = fmaf(hh, sWe2[j * 6 + c], acc[c]);
        }
        unsigned z = pk_fp8x4(acc[0], acc[1], acc[2], acc[3]);
        unsigned w = pk_fp8x2(acc[4], acc[5]);
        int p0 = atomicAdd(&cur[s >> 8], 1);
        rec[p0] = make_uint4((unsigned)(s << 1), 0u, z, w);
        int p1 = atomicAdd(&cur[d >> 8], 1);
        rec[p1] = make_uint4((unsigned)(d << 1) | 1u, (unsigned)s, z, w);
    }
}

// ------- B: per-bucket: nef/deg/indeg in LDS -> xp, dinv, offI, in_src ------
__global__ __launch_bounds__(256) void k_B(
    const uint4* __restrict__ rec, const int* __restrict__ hs,
    const int* __restrict__ inBase, const float* __restrict__ x,
    float* __restrict__ xp, float* __restrict__ dinv,
    int* __restrict__ offI, int* __restrict__ in_src, int E, int N) {
    __shared__ float nef[NPB * 6];
    __shared__ int degAll[NPB], degIn[NPB], rnk[NPB], sc[NPB], exO[NPB];
    int t = threadIdx.x, b = blockIdx.x;
#pragma unroll
    for (int c = 0; c < 6; ++c) nef[t * 6 + c] = 0.f;
    degAll[t] = 0; degIn[t] = 0; rnk[t] = 0;
    __syncthreads();

    int rb = hs[(size_t)b * NBLKA];
    int re = (b == NB - 1) ? 2 * E : hs[(size_t)(b + 1) * NBLKA];
    for (int j = rb + t; j < re; j += 256) {
        uint4 r = rec[j];
        int l = (int)((r.x >> 1) & 255u);
        atomicAdd(&degAll[l], 1);
        if (r.x & 1u) atomicAdd(&degIn[l], 1);
        floatx2 p01 = __builtin_amdgcn_cvt_pk_f32_fp8(r.z, false);
        floatx2 p23 = __builtin_amdgcn_cvt_pk_f32_fp8(r.z, true);
        floatx2 p45 = __builtin_amdgcn_cvt_pk_f32_fp8(r.w, false);
        atomicAdd(&nef[l * 6 + 0], p01.x);
        atomicAdd(&nef[l * 6 + 1], p01.y);
        atomicAdd(&nef[l * 6 + 2], p23.x);
        atomicAdd(&nef[l * 6 + 3], p23.y);
        atomicAdd(&nef[l * 6 + 4], p45.x);
        atomicAdd(&nef[l * 6 + 5], p45.y);
    }
    __syncthreads();

    // exclusive LDS scan of degIn
    int v = degIn[t];
    sc[t] = v;
    __syncthreads();
    for (int s = 1; s < 256; s <<= 1) {
        int tmp = (t >= s) ? sc[t - s] : 0;
        __syncthreads();
        sc[t] += tmp;
        __syncthreads();
    }
    exO[t] = sc[t] - v;
    __syncthreads();

    int node = b * NPB + t;
    int ib = inBase[b];
    if (node <= N) offI[node] = ib + exO[t];  // node==N -> offI[N]=E
    if (node < N) {
        float da = (float)degAll[t];
        float inv = 0.5f / fmaxf(da, 1.f);
        const float2* xr = (const float2*)(x + (size_t)node * 6);
        float2 x01 = xr[0], x23 = xr[1], x45 = xr[2];
        float2* xw = (float2*)(xp + (size_t)node * 6);
        xw[0] = make_float2(x01.x + nef[t * 6 + 0] * inv, x01.y + nef[t * 6 + 1] * inv);
        xw[1] = make_float2(x23.x + nef[t * 6 + 2] * inv, x23.y + nef[t * 6 + 3] * inv);
        xw[2] = make_float2(x45.x + nef[t * 6 + 4] * inv, x45.y + nef[t * 6 + 5] * inv);
        dinv[node] = 1.f / sqrtf(1.f + (float)degIn[t]);
    }
    __syncthreads();

    // sweep 2: build in-CSR (scattered writes stay within L2-resident region)
    for (int j = rb + t; j < re; j += 256) {
        uint4 r = rec[j];
        if (r.x & 1u) {
            int l = (int)((r.x >> 1) & 255u);
            int k = atomicAdd(&rnk[l], 1);
            in_src[ib + exO[l] + k] = (int)r.y;
        }
    }
}

// ------- layer 1: s1 = fp8(dinv * (x'(N,6) @ W1)), rows = 16 uints ----------
__global__ __launch_bounds__(256) void k_mm1(const float* __restrict__ xp,
                                             const float* __restrict__ W1,
                                             const float* __restrict__ dinv,
                                             unsigned* __restrict__ sOut, int n) {
    int lane = threadIdx.x & 63;
    int sub = lane & 15;
    int wid = (blockIdx.x * blockDim.x + threadIdx.x) >> 6;
    int nw = (gridDim.x * blockDim.x) >> 6;
    float w[6];
#pragma unroll
    for (int c = 0; c < 6; ++c) w[c] = W1[c * 64 + lane];
    for (int i = wid; i < n; i += nw) {
        float xv = (lane < 6) ? xp[(size_t)i * 6 + lane] : 0.f;
        float acc = 0.f;
#pragma unroll
        for (int c = 0; c < 6; ++c) acc = fmaf(rdlane(xv, c), w[c], acc);
        float o = acc * dinv[i];
        float o0 = __shfl(o, sub * 4 + 0);
        float o1 = __shfl(o, sub * 4 + 1);
        float o2 = __shfl(o, sub * 4 + 2);
        float o3 = __shfl(o, sub * 4 + 3);
        if (lane < 16) sOut[(size_t)i * 16 + lane] = pk_fp8x4(o0, o1, o2, o3);
    }
}

// ------- FUSED gather+mm, fp8 rows (64B): 16 lanes x uint per row -----------
__global__ __launch_bounds__(256) void k_gathermm(
    const int* __restrict__ offI, const int* __restrict__ in_src,
    const float* __restrict__ dinv, const unsigned* __restrict__ sIn,
    const float* __restrict__ bias, const float* __restrict__ W,
    unsigned* __restrict__ sOut, int n) {
    int lane = threadIdx.x & 63;
    int sub = lane & 15, grp = lane >> 4;
    int wid = (blockIdx.x * blockDim.x + threadIdx.x) >> 6;
    int nw = (gridDim.x * blockDim.x) >> 6;
    float w[64];
#pragma unroll
    for (int c = 0; c < 64; ++c) w[c] = W[c * 64 + lane];
    float4 bb = ((const float4*)bias)[sub];

    for (int i = wid; i < n; i += nw) {
        unsigned su = sIn[(size_t)i * 16 + sub];
        float a0, a1, a2, a3;
        if (grp == 0) {
            floatx2 lo = __builtin_amdgcn_cvt_pk_f32_fp8(su, false);
            floatx2 hi = __builtin_amdgcn_cvt_pk_f32_fp8(su, true);
            a0 = lo.x; a1 = lo.y; a2 = hi.x; a3 = hi.y;
        } else { a0 = a1 = a2 = a3 = 0.f; }
        int b0 = offI[i], e0 = offI[i + 1];
#pragma unroll 4
        for (int j = b0 + grp; j < e0; j += 4) {
            unsigned src = (unsigned)in_src[j];
            unsigned u = sIn[(size_t)src * 16 + sub];
            floatx2 lo = __builtin_amdgcn_cvt_pk_f32_fp8(u, false);
            floatx2 hi = __builtin_amdgcn_cvt_pk_f32_fp8(u, true);
            a0 += lo.x; a1 += lo.y; a2 += hi.x; a3 += hi.y;
        }
        a0 += __shfl_xor(a0, 16); a1 += __shfl_xor(a1, 16);
        a2 += __shfl_xor(a2, 16); a3 += __shfl_xor(a3, 16);
        a0 += __shfl_xor(a0, 32); a1 += __shfl_xor(a1, 32);
        a2 += __shfl_xor(a2, 32); a3 += __shfl_xor(a3, 32);

        float dv = dinv[i];
        float h0 = fmaxf(fmaf(a0, dv, bb.x), 0.f);
        float h1 = fmaxf(fmaf(a1, dv, bb.y), 0.f);
        float h2 = fmaxf(fmaf(a2, dv, bb.z), 0.f);
        float h3 = fmaxf(fmaf(a3, dv, bb.w), 0.f);
        float o = 0.f;
#pragma unroll
        for (int g = 0; g < 16; ++g) {
            o = fmaf(rdlane(h0, g), w[g * 4 + 0], o);
            o = fmaf(rdlane(h1, g), w[g * 4 + 1], o);
            o = fmaf(rdlane(h2, g), w[g * 4 + 2], o);
            o = fmaf(rdlane(h3, g), w[g * 4 + 3], o);
        }
        o *= dv;
        float o0 = __shfl(o, sub * 4 + 0);
        float o1 = __shfl(o, sub * 4 + 1);
        float o2 = __shfl(o, sub * 4 + 2);
        float o3 = __shfl(o, sub * 4 + 3);
        if (lane < 16) sOut[(size_t)i * 16 + lane] = pk_fp8x4(o0, o1, o2, o3);
    }
}

// ------- FUSED final gather + b3 + pooled sum/sumsq, fp8 rows ---------------
__global__ __launch_bounds__(256) void k_gatherreduce(
    const int* __restrict__ offI, const int* __restrict__ in_src,
    const float* __restrict__ dinv, const unsigned* __restrict__ sIn,
    const float* __restrict__ b3, double* __restrict__ sums, int n) {
    int lane = threadIdx.x & 63;
    int sub = lane & 15, grp = lane >> 4;
    int wv = threadIdx.x >> 6;
    int wid = (blockIdx.x * blockDim.x + threadIdx.x) >> 6;
    int nw = (gridDim.x * blockDim.x) >> 6;
    float4 bb = ((const float4*)b3)[sub];
    double s0 = 0.0, s1 = 0.0, s2_ = 0.0, s3 = 0.0;
    double q0 = 0.0, q1 = 0.0, q2 = 0.0, q3 = 0.0;

    for (int i = wid; i < n; i += nw) {
        unsigned su = sIn[(size_t)i * 16 + sub];
        float a0, a1, a2, a3;
        if (grp == 0) {
            floatx2 lo = __builtin_amdgcn_cvt_pk_f32_fp8(su, false);
            floatx2 hi = __builtin_amdgcn_cvt_pk_f32_fp8(su, true);
            a0 = lo.x; a1 = lo.y; a2 = hi.x; a3 = hi.y;
        } else { a0 = a1 = a2 = a3 = 0.f; }
        int b0 = offI[i], e0 = offI[i + 1];
#pragma unroll 4
        for (int j = b0 + grp; j < e0; j += 4) {
            unsigned src = (unsigned)in_src[j];
            unsigned u = sIn[(size_t)src * 16 + sub];
            floatx2 lo = __builtin_amdgcn_cvt_pk_f32_fp8(u, false);
            floatx2 hi = __builtin_amdgcn_cvt_pk_f32_fp8(u, true);
            a0 += lo.x; a1 += lo.y; a2 += hi.x; a3 += hi.y;
        }
        a0 += __shfl_xor(a0, 16); a1 += __shfl_xor(a1, 16);
        a2 += __shfl_xor(a2, 16); a3 += __shfl_xor(a3, 16);
        a0 += __shfl_xor(a0, 32); a1 += __shfl_xor(a1, 32);
        a2 += __shfl_xor(a2, 32); a3 += __shfl_xor(a3, 32);

        float dv = dinv[i];
        float v0 = fmaf(a0, dv, bb.x);
        float v1 = fmaf(a1, dv, bb.y);
        float v2 = fmaf(a2, dv, bb.z);
        float v3 = fmaf(a3, dv, bb.w);
        s0 += v0; s1 += v1; s2_ += v2; s3 += v3;
        q0 += (double)v0 * v0; q1 += (double)v1 * v1;
        q2 += (double)v2 * v2; q3 += (double)v3 * v3;
    }
    __shared__ double shS[4 * 64], shQ[4 * 64];
    if (grp == 0) {
#pragma unroll
        for (int k = 0; k < 4; ++k) {
            double sk = (k == 0) ? s0 : (k == 1) ? s1 : (k == 2) ? s2_ : s3;
            double qk = (k == 0) ? q0 : (k == 1) ? q1 : (k == 2) ? q2 : q3;
            shS[wv * 64 + sub * 4 + k] = sk;
            shQ[wv * 64 + sub * 4 + k] = qk;
        }
    }
    __syncthreads();
    if (wv == 0) {
        double a = shS[lane] + shS[64 + lane] + shS[128 + lane] + shS[192 + lane];
        double c = shQ[lane] + shQ[64 + lane] + shQ[128 + lane] + shQ[192 + lane];
        unsafeAtomicAdd(&sums[lane], a);
        unsafeAtomicAdd(&sums[64 + lane], c);
    }
}

// ---------------- head MLP + sigmoid (single block) -------------------------
__global__ void k_head(const double* __restrict__ sums,
                       const float* __restrict__ Wp1, const float* __restrict__ bp1,
                       const float* __restrict__ Wp2, const float* __restrict__ bp2,
                       const float* __restrict__ Wp3, const float* __restrict__ bp3,
                       float* __restrict__ out, int n) {
    __shared__ float comb[192], p1[64], p2[32];
    int t = threadIdx.x;
    if (t < 64) {
        double s = sums[t], s2 = sums[64 + t];
        double m = s / n;
        double var = (s2 - s * s / n) / (double)(n - 1);
        float mf = (float)m;
        float sd = (float)sqrt(var > 0.0 ? var : 0.0);
        comb[t] = mf;
        comb[64 + t] = mf;
        comb[128 + t] = sd;
    }
    __syncthreads();
    if (t < 64) {
        float acc = bp1[t];
        for (int k = 0; k < 192; ++k) acc = fmaf(comb[k], Wp1[k * 64 + t], acc);
        p1[t] = fmaxf(acc, 0.f);
    }
    __syncthreads();
    if (t < 32) {
        float acc = bp2[t];
        for (int k = 0; k < 64; ++k) acc = fmaf(p1[k], Wp2[k * 32 + t], acc);
        p2[t] = fmaxf(acc, 0.f);
    }
    __syncthreads();
    if (t == 0) {
        float acc = bp3[0];
        for (int k = 0; k < 32; ++k) acc = fmaf(p2[k], Wp3[k], acc);
        out[0] = 1.f / (1.f + expf(-acc));
    }
}

static inline char* align16(char* p) {
    return (char*)(((uintptr_t)p + 15) & ~(uintptr_t)15);
}

extern "C" void kernel_launch(void* const* d_in, const int* in_sizes, int n_in,
                              void* d_out, int out_size, void* d_ws, size_t ws_size,
                              hipStream_t stream) {
    const float* x   = (const float*)d_in[0];
    const int*   ei  = (const int*)d_in[1];
    const float* ea  = (const float*)d_in[2];
    const float* W1  = (const float*)d_in[3];
    const float* b1  = (const float*)d_in[4];
    const float* W2  = (const float*)d_in[5];
    const float* b2  = (const float*)d_in[6];
    const float* W3  = (const float*)d_in[7];
    const float* b3  = (const float*)d_in[8];
    const float* We1 = (const float*)d_in[9];
    const float* be1 = (const float*)d_in[10];
    const float* We2 = (const float*)d_in[11];
    const float* be2 = (const float*)d_in[12];
    const float* Wp1 = (const float*)d_in[13];
    const float* bp1 = (const float*)d_in[14];
    const float* Wp2 = (const float*)d_in[15];
    const float* bp2 = (const float*)d_in[16];
    const float* Wp3 = (const float*)d_in[17];
    const float* bp3 = (const float*)d_in[18];

    const int N = in_sizes[0] / 6;
    const int E = in_sizes[1] / 2;
    const int epb = (E + NBLKA - 1) / NBLKA;
    const int HSZ = NB * NBLKA;                 // 200192
    const int nScan = (HSZ + 511) / 512;        // 391
    const size_t SB = (size_t)N * 64;           // fp8 table = 6.4MB

    // ---- workspace layout (~62 MB) ----
    char* p = (char*)d_ws;
    double* sums = (double*)p;          p = align16(p + 128 * sizeof(double));
    int* inTot = (int*)p;               p = align16(p + NB * 4);
    int* inBase = (int*)p;              p = align16(p + NB * 4);
    int* bsum = (int*)p;                p = align16(p + 512 * 4);
    int* h = (int*)p;                   p = align16(p + (size_t)HSZ * 4);
    float* xp = (float*)p;              p = align16(p + (size_t)N * 6 * 4);
    float* dinv = (float*)p;            p = align16(p + (size_t)N * 4);
    int* offI = (int*)p;                p = align16(p + ((size_t)N + 1) * 4);
    int* in_src = (int*)p;              p = align16(p + (size_t)E * 4);
    // U: records (2E*16B = 51.2MB) die after k_B; sbufA/B reborn inside
    char* u = p;
    uint4* rec = (uint4*)u;
    unsigned* sbufA = (unsigned*)u;
    unsigned* sbufB = (unsigned*)(u + ((SB + 15) & ~(size_t)15));

    dim3 blk(256);

    k_zero<<<dim3(1), dim3(512), 0, stream>>>(inTot, sums);
    k_A1<<<dim3(NBLKA), blk, 0, stream>>>(ei, h, inTot, E, epb);
    k_sc1<<<dim3(nScan), dim3(512), 0, stream>>>(h, bsum, HSZ);
    k_sc2<<<dim3(1), dim3(512), 0, stream>>>(bsum, nScan);
    k_sc3<<<dim3(nScan), dim3(512), 0, stream>>>(h, bsum, HSZ);
    k_scanIn<<<dim3(1), dim3(512), 0, stream>>>(inTot, inBase);
    k_A2<<<dim3(NBLKA), blk, 0, stream>>>(ei, ea, We1, be1, We2, be2, h, rec, E, epb);
    k_B<<<dim3(NB), blk, 0, stream>>>(rec, h, inBase, x, xp, dinv, offI, in_src, E, N);

    // layer 1 matmul (sbufA aliases records — dead after k_B)
    k_mm1<<<dim3(1024), blk, 0, stream>>>(xp, W1, dinv, sbufA, N);
    // layers 2,3 fused gather+mm; final fused gather+reduce
    k_gathermm<<<dim3(2048), blk, 0, stream>>>(offI, in_src, dinv, sbufA, b1, W2, sbufB, N);
    k_gathermm<<<dim3(2048), blk, 0, stream>>>(offI, in_src, dinv, sbufB, b2, W3, sbufA, N);
    k_gatherreduce<<<dim3(2048), blk, 0, stream>>>(offI, in_src, dinv, sbufA, b3, sums, N);
    k_head<<<dim3(1), dim3(64), 0, stream>>>(sums, Wp1, bp1, Wp2, bp2, Wp3, bp3,
                                             (float*)d_out, N);
}